// Round 8
// baseline (2263.738 us; speedup 1.0000x reference)
//
#include <hip/hip_runtime.h>
#include <hip/hip_bf16.h>

#define T_STEPS 512
#define BATCH   1024
#define HD1     80
#define HD2     100
#define NB      2       // batches per block (lstm2)

#define W1_DW   (HD1 / 2)              // 40 packed dwords per lstm1 row
#define W2_DW   ((HD1 + HD2) / 2)      // 90 packed dwords per lstm2 row
#define NR1     (4 * HD1)              // 320 rows
#define NR2     (4 * HD2)              // 400 rows

typedef _Float16 half2_t __attribute__((ext_vector_type(2)));

static __device__ __forceinline__ half2_t bch(unsigned int u) {
    return __builtin_bit_cast(half2_t, u);
}
static __device__ __forceinline__ unsigned int bcu(half2_t h) {
    return __builtin_bit_cast(unsigned int, h);
}

static __device__ __forceinline__ float dot2(half2_t a, half2_t b, float c) {
    return __builtin_amdgcn_fdot2(a, b, c, false);
}

static __device__ __forceinline__ unsigned int packh(float a, float b) {
    half2_t p; p.x = (_Float16)a; p.y = (_Float16)b; return bcu(p);
}

// Pin a value into a VGPR: the asm becomes its def, so the backend cannot
// rematerialize the originating load inside the loop.
#define PIN(v) asm volatile("" : "+v"(v))

// ---------------------------------------------------------------------------
// Prep: pack weights to f16 dwords, transposed [dword][row] for coalescing.
// ---------------------------------------------------------------------------
__global__ __launch_bounds__(256)
void prep_kernel(const float* __restrict__ W_hh1,
                 const float* __restrict__ W_ih2,
                 const float* __restrict__ W_hh2,
                 unsigned int* __restrict__ w1t,
                 unsigned int* __restrict__ w2t)
{
    int i = blockIdx.x * 256 + threadIdx.x;
    if (i < W1_DW * NR1) {
        int d = i / NR1, j = i % NR1;
        w1t[i] = packh(W_hh1[j * HD1 + 2 * d], W_hh1[j * HD1 + 2 * d + 1]);
    } else if (i < W1_DW * NR1 + W2_DW * NR2) {
        int k = i - W1_DW * NR1;
        int d = k / NR2, j = k % NR2;
        unsigned int p;
        if (d < W1_DW)
            p = packh(W_ih2[j * HD1 + 2 * d], W_ih2[j * HD1 + 2 * d + 1]);
        else {
            int dd = d - W1_DW;
            p = packh(W_hh2[j * HD2 + 2 * dd], W_hh2[j * HD2 + 2 * dd + 1]);
        }
        w2t[k] = p;
    }
}

// ---------------------------------------------------------------------------
// Phase 1: LSTM layer 1, ONE batch per block (1024 blocks x 320 threads).
// Round-7 structure + pinned weights (forces 40 dwords VGPR-resident;
// 40 + ~20 misc fits the 64-reg / 8-waves-per-EU budget).
// ---------------------------------------------------------------------------
__global__ __launch_bounds__(NR1, 4)
void lstm1_kernel(const float* __restrict__ x,
                  const float* __restrict__ W_ih1,
                  const unsigned int* __restrict__ w1t,
                  const float* __restrict__ b_ih1,
                  const float* __restrict__ b_hh1,
                  _Float16* __restrict__ h1relu)
{
    const int j = threadIdx.x;
    const int b = blockIdx.x;
    const int q = j / HD1;
    const int m = j % HD1;

    unsigned int w[W1_DW];
#pragma unroll
    for (int d = 0; d < W1_DW; d++) {
        unsigned int v = w1t[d * NR1 + j];
        PIN(v);
        w[d] = v;
    }
    const float wih  = W_ih1[j];
    const float bias = b_ih1[j] + b_hh1[j];

    __shared__ uint4 hp[HD1 / 8];     // 10 entries, 8 f16 values each
    __shared__ float gates[NR1];
    __shared__ float xs[T_STEPS];

    if (j < HD1 / 8) hp[j] = make_uint4(0u, 0u, 0u, 0u);
    for (int idx = j; idx < T_STEPS; idx += NR1)
        xs[idx] = x[(size_t)b * T_STEPS + idx];
    float c = 0.f;
    __syncthreads();

    for (int t = 0; t < T_STEPS; t++) {
        float accP = fmaf(wih, xs[t], bias);
        float accQ = 0.f;
#pragma unroll
        for (int k4 = 0; k4 < HD1 / 8; k4++) {
            uint4 U = hp[k4];
            accP = dot2(bch(w[4 * k4 + 0]), bch(U.x), accP);
            accQ = dot2(bch(w[4 * k4 + 1]), bch(U.y), accQ);
            accP = dot2(bch(w[4 * k4 + 2]), bch(U.z), accP);
            accQ = dot2(bch(w[4 * k4 + 3]), bch(U.w), accQ);
        }
        float z = accP + accQ;
        z = (q == 2) ? 2.f * z : z;
        float s = 1.f / (1.f + __expf(-z));
        gates[j] = (q == 2) ? (2.f * s - 1.f) : s;
        __syncthreads();                      // gates ready

        if (j < HD1) {
            float gi = gates[m];
            float gf = gates[HD1 + m];
            float gg = gates[2 * HD1 + m];
            float go = gates[3 * HD1 + m];
            c = fmaf(gf, c, gi * gg);
            float th = 2.f / (1.f + __expf(-2.f * c)) - 1.f;
            float h = go * th;
            float hn = __shfl_down(h, 1, 64);
            if ((m & 1) == 0) {
                ((unsigned int*)hp)[m >> 1] = packh(h, hn);
                *(unsigned int*)(h1relu + ((size_t)t * BATCH + b) * HD1 + m) =
                    packh(fmaxf(h, 0.f), fmaxf(hn, 0.f));
            }
        }
        __syncthreads();                      // hp(t+1) ready
    }
}

// ---------------------------------------------------------------------------
// Phase 2: LSTM layer 2. 512 blocks x 512 threads, 2 batches/block.
// Round-4 structure + (512,2) reg budget (grants ~128) + pinned weights
// (90 dwords provably resident; no scratch traffic).
// ---------------------------------------------------------------------------
__global__ __launch_bounds__(512, 2)
void lstm2_kernel(const _Float16* __restrict__ h1relu,
                  const unsigned int* __restrict__ w2t,
                  const float* __restrict__ b_ih2,
                  const float* __restrict__ b_hh2,
                  float* __restrict__ h2last)
{
    const int j  = threadIdx.x;
    const int b0 = blockIdx.x * NB;
    const int jr = (j < NR2) ? j : (NR2 - 1);   // clamp: loads unconditional
    const bool rowActive = (j < NR2);
    const int q = jr / HD2;
    const int m = jr % HD2;

    unsigned int w[W2_DW];
#pragma unroll
    for (int d = 0; d < W2_DW; d++) {
        unsigned int v = w2t[d * NR2 + jr];
        PIN(v);
        w[d] = v;
    }
    const float bias = b_ih2[jr] + b_hh2[jr];

    __shared__ uint4  h1p[HD1 / 4];    // 20: {b0 pair, b1 pair, b0 pair, b1 pair}
    __shared__ uint4  h2p[HD2 / 4];    // 25, same layout
    __shared__ float2 gates[NR2];

    if (j < HD2 / 4) h2p[j] = make_uint4(0u, 0u, 0u, 0u);
    float c0 = 0.f, c1 = 0.f;

    // stagers: threads 400..479
    const int  sj = j - NR2;
    const bool stager = (sj >= 0) && (sj < NB * W1_DW);
    const int  pb  = (sj >= 0 ? sj : 0) / W1_DW;
    const int  pk2 = (sj >= 0 ? sj : 0) % W1_DW;
    const int  sidx = 4 * (pk2 >> 1) + 2 * (pk2 & 1) + pb;
    unsigned int pf = 0;
    if (stager)
        pf = *(const unsigned int*)(h1relu + ((size_t)b0 + pb) * HD1 + 2 * pk2);

    for (int t = 0; t < T_STEPS; t++) {
        if (stager)
            ((unsigned int*)h1p)[sidx] = pf;   // stage h1(t)
        __syncthreads();                       // h1p(t) + h2p(t) ready

        if (stager && t + 1 < T_STEPS)
            pf = *(const unsigned int*)(h1relu +
                     ((size_t)(t + 1) * BATCH + b0 + pb) * HD1 + 2 * pk2);

        // dots on ALL threads (uniform control flow; garbage for j>=400)
        float a0P = bias, a0Q = 0.f, a1P = bias, a1Q = 0.f;
#pragma unroll
        for (int k4 = 0; k4 < HD1 / 4; k4++) {
            uint4 U = h1p[k4];
            a0P = dot2(bch(w[2 * k4]),     bch(U.x), a0P);
            a1P = dot2(bch(w[2 * k4]),     bch(U.y), a1P);
            a0Q = dot2(bch(w[2 * k4 + 1]), bch(U.z), a0Q);
            a1Q = dot2(bch(w[2 * k4 + 1]), bch(U.w), a1Q);
        }
#pragma unroll
        for (int k4 = 0; k4 < HD2 / 4; k4++) {
            uint4 U = h2p[k4];
            a0P = dot2(bch(w[W1_DW + 2 * k4]),     bch(U.x), a0P);
            a1P = dot2(bch(w[W1_DW + 2 * k4]),     bch(U.y), a1P);
            a0Q = dot2(bch(w[W1_DW + 2 * k4 + 1]), bch(U.z), a0Q);
            a1Q = dot2(bch(w[W1_DW + 2 * k4 + 1]), bch(U.w), a1Q);
        }
        float z0 = a0P + a0Q;
        float z1 = a1P + a1Q;
        z0 = (q == 2) ? 2.f * z0 : z0;
        z1 = (q == 2) ? 2.f * z1 : z1;
        float s0 = 1.f / (1.f + __expf(-z0));
        float s1 = 1.f / (1.f + __expf(-z1));
        if (rowActive)
            gates[j] = make_float2((q == 2) ? (2.f * s0 - 1.f) : s0,
                                   (q == 2) ? (2.f * s1 - 1.f) : s1);
        __syncthreads();                       // gates ready

        if (j < HD2) {
            float2 gi = gates[m];
            float2 gf = gates[HD2 + m];
            float2 gg = gates[2 * HD2 + m];
            float2 go = gates[3 * HD2 + m];
            c0 = fmaf(gf.x, c0, gi.x * gg.x);
            c1 = fmaf(gf.y, c1, gi.y * gg.y);
            float t0 = 2.f / (1.f + __expf(-2.f * c0)) - 1.f;
            float t1 = 2.f / (1.f + __expf(-2.f * c1)) - 1.f;
            float h0 = go.x * t0;
            float h1 = go.y * t1;
            float h0n = __shfl_down(h0, 1, 64);
            float h1n = __shfl_down(h1, 1, 64);
            if ((m & 1) == 0) {
                int p = m >> 1;
                int idx0 = 4 * (p >> 1) + 2 * (p & 1);   // even → uint2-aligned
                ((uint2*)h2p)[idx0 >> 1] =
                    make_uint2(packh(h0, h0n), packh(h1, h1n));
            }
            if (t == T_STEPS - 1) {
                h2last[(size_t)(b0 + 0) * HD2 + m] = fmaxf(h0, 0.f);
                h2last[(size_t)(b0 + 1) * HD2 + m] = fmaxf(h1, 0.f);
            }
        }
        // next loop-top stage + barrier covers h2p visibility
    }
}

// ---------------------------------------------------------------------------
// Head: out[b] = W_l2 @ relu(W_l1 @ h2last[b] + b_l1) + b_l2
// ---------------------------------------------------------------------------
__global__ __launch_bounds__(64)
void head_kernel(const float* __restrict__ h2last,
                 const float* __restrict__ W_l1,
                 const float* __restrict__ b_l1,
                 const float* __restrict__ W_l2,
                 const float* __restrict__ b_l2,
                 float* __restrict__ out)
{
    int b = blockIdx.x * 64 + threadIdx.x;
    if (b >= BATCH) return;
    const float* h = h2last + (size_t)b * HD2;
    float o = b_l2[0];
#pragma unroll
    for (int u = 0; u < 10; u++) {
        float s = b_l1[u];
#pragma unroll
        for (int k = 0; k < HD2; k++) s = fmaf(W_l1[u * HD2 + k], h[k], s);
        o = fmaf(W_l2[u], fmaxf(s, 0.f), o);
    }
    out[b] = o;
}

extern "C" void kernel_launch(void* const* d_in, const int* in_sizes, int n_in,
                              void* d_out, int out_size, void* d_ws, size_t ws_size,
                              hipStream_t stream)
{
    const float* x     = (const float*)d_in[0];
    const float* W_ih1 = (const float*)d_in[1];
    const float* W_hh1 = (const float*)d_in[2];
    const float* b_ih1 = (const float*)d_in[3];
    const float* b_hh1 = (const float*)d_in[4];
    const float* W_ih2 = (const float*)d_in[5];
    const float* W_hh2 = (const float*)d_in[6];
    const float* b_ih2 = (const float*)d_in[7];
    const float* b_hh2 = (const float*)d_in[8];
    const float* W_l1  = (const float*)d_in[9];
    const float* b_l1  = (const float*)d_in[10];
    const float* W_l2  = (const float*)d_in[11];
    const float* b_l2  = (const float*)d_in[12];
    float* out = (float*)d_out;

    // ws layout: h1relu f16 [t][b][k] (84 MB) | h2last f32 | w1t | w2t
    char* p = (char*)d_ws;
    _Float16* h1relu = (_Float16*)p;           p += (size_t)T_STEPS * BATCH * HD1 * 2;
    float* h2last    = (float*)p;              p += (size_t)BATCH * HD2 * 4;
    unsigned int* w1t = (unsigned int*)p;      p += (size_t)W1_DW * NR1 * 4;
    unsigned int* w2t = (unsigned int*)p;

    int prep_n = W1_DW * NR1 + W2_DW * NR2;
    hipLaunchKernelGGL(prep_kernel, dim3((prep_n + 255) / 256), dim3(256), 0, stream,
                       W_hh1, W_ih2, W_hh2, w1t, w2t);
    hipLaunchKernelGGL(lstm1_kernel, dim3(BATCH), dim3(NR1), 0, stream,
                       x, W_ih1, w1t, b_ih1, b_hh1, h1relu);
    hipLaunchKernelGGL(lstm2_kernel, dim3(BATCH / NB), dim3(512), 0, stream,
                       h1relu, w2t, b_ih2, b_hh2, h2last);
    hipLaunchKernelGGL(head_kernel, dim3(BATCH / 64), dim3(64), 0, stream,
                       h2last, W_l1, b_l1, W_l2, b_l2, out);
}

// Round 9
// 2090.417 us; speedup vs baseline: 1.0829x; 1.0829x over previous
//
#include <hip/hip_runtime.h>
#include <hip/hip_bf16.h>

#define T_STEPS 512
#define BATCH   1024
#define HD1     80
#define HD2     100
#define W1ROW   128    // padded K, layer1: [h1(80) | x(1) | 0...]
#define W2ROW   192    // padded K, layer2: [relu_h1(80) | h2(100) | 0...]

typedef _Float16 f16x8 __attribute__((ext_vector_type(8)));
typedef float    f32x4 __attribute__((ext_vector_type(4)));
typedef _Float16 half2_t __attribute__((ext_vector_type(2)));

static __device__ __forceinline__ unsigned int packh(float a, float b) {
    half2_t p; p.x = (_Float16)a; p.y = (_Float16)b;
    return __builtin_bit_cast(unsigned int, p);
}
static __device__ __forceinline__ float sigm(float z)  { return 1.f / (1.f + __expf(-z)); }
static __device__ __forceinline__ float tanh_(float z) { return 2.f / (1.f + __expf(-2.f * z)) - 1.f; }

// ---------------------------------------------------------------------------
// Prep: K-padded f16 weight matrices, row-major [row][K].
// wpad1[320][128]: k<80 = W_hh1[r][k]; k==80 = W_ih1[r]; else 0.
// wpad2[400][192]: k<80 = W_ih2[r][k]; 80<=k<180 = W_hh2[r][k-80]; else 0.
// ---------------------------------------------------------------------------
__global__ __launch_bounds__(256)
void prep_kernel(const float* __restrict__ W_ih1, const float* __restrict__ W_hh1,
                 const float* __restrict__ W_ih2, const float* __restrict__ W_hh2,
                 _Float16* __restrict__ wpad1, _Float16* __restrict__ wpad2)
{
    int i = blockIdx.x * 256 + threadIdx.x;
    if (i < 320 * W1ROW) {
        int r = i / W1ROW, k = i % W1ROW;
        float v = 0.f;
        if (k < 80) v = W_hh1[r * 80 + k];
        else if (k == 80) v = W_ih1[r];
        wpad1[i] = (_Float16)v;
    } else {
        int j = i - 320 * W1ROW;
        if (j < 400 * W2ROW) {
            int r = j / W2ROW, k = j % W2ROW;
            float v = 0.f;
            if (k < 80) v = W_ih2[r * 80 + k];
            else if (k < 180) v = W_hh2[r * 100 + (k - 80)];
            wpad2[j] = (_Float16)v;
        }
    }
}

// ---------------------------------------------------------------------------
// LSTM layer 1, MFMA. 64 blocks x 320 threads (5 waves), M=16 batches/block.
// Wave wv owns gate rows [64wv,64wv+64) = 4 N-tiles; B-frags (4x4x4=64 VGPR)
// persistent. State LDS: 16 rows x 64 dwords (f16 pairs), XOR-swizzled b128
// groups (g ^ (m&7)) -> conflict-free A loads. K=128: h1(80), x(1), pad.
// 2 barriers/step.
// ---------------------------------------------------------------------------
__global__ __launch_bounds__(320, 2)
void lstm1_kernel(const float* __restrict__ x,
                  const _Float16* __restrict__ wpad1,
                  const float* __restrict__ b_ih1,
                  const float* __restrict__ b_hh1,
                  unsigned int* __restrict__ h1dw)   // relu(h1) f16 pairs [t][b][40]
{
    const int tid  = threadIdx.x;
    const int lane = tid & 63;
    const int wv   = tid >> 6;      // 0..4
    const int ln16 = lane & 15;
    const int q    = lane >> 4;     // 0..3
    const int b0   = blockIdx.x * 16;

    // B fragments: lane holds W[n = tile*16 + ln16][k = 32*kk + 8*q .. +8)
    f16x8 bw[4][4];
    {
        const uint4* wp = (const uint4*)wpad1;   // row = 16 uint4 groups
        #pragma unroll
        for (int tt = 0; tt < 4; tt++) {
            int r = 64 * wv + 16 * tt + ln16;
            #pragma unroll
            for (int kk = 0; kk < 4; kk++)
                bw[tt][kk] = __builtin_bit_cast(f16x8, wp[r * 16 + 4 * kk + q]);
        }
    }

    __shared__ unsigned int st[16 * 64];     // state, swizzled groups, 4KB
    __shared__ float gbuf[320 * 17];         // gate pre-acts [n][m], 21.8KB
    __shared__ float xs[16][T_STEPS];        // 32KB

    for (int i = tid; i < 16 * T_STEPS; i += 320)
        xs[i >> 9][i & 511] = x[(size_t)(b0 + (i >> 9)) * T_STEPS + (i & 511)];
    for (int i = tid; i < 16 * 64; i += 320) st[i] = 0u;

    // epilogue mapping (tid<160): ej = unit-pair 0..39, emg = m-group 0..3
    const int ej = tid % 40, emg = (tid / 40) & 3;
    float cst[2][4] = {};
    float bia[2][4];
    if (tid < 160) {
        #pragma unroll
        for (int e = 0; e < 2; e++) {
            int u = 2 * ej + e;
            #pragma unroll
            for (int g = 0; g < 4; g++)
                bia[e][g] = b_ih1[g * 80 + u] + b_hh1[g * 80 + u];
        }
    }
    __syncthreads();
    if (tid < 16)    // x(0) at k=80 -> dword d=40 -> group 10, pos 0
        st[tid * 64 + ((10 ^ (tid & 7)) << 2)] = packh(xs[tid][0], 0.f);

    for (int t = 0; t < T_STEPS; t++) {
        __syncthreads();                     // state(t) ready
        f16x8 af[4];
        #pragma unroll
        for (int kk = 0; kk < 4; kk++) {
            int g = 4 * kk + q;
            af[kk] = __builtin_bit_cast(f16x8,
                *(const uint4*)&st[ln16 * 64 + ((g ^ (ln16 & 7)) << 2)]);
        }
        #pragma unroll
        for (int tt = 0; tt < 4; tt++) {
            f32x4 acc = {0.f, 0.f, 0.f, 0.f};
            #pragma unroll
            for (int kk = 0; kk < 4; kk++)
                acc = __builtin_amdgcn_mfma_f32_16x16x32_f16(af[kk], bw[tt][kk], acc, 0, 0, 0);
            int n = 64 * wv + 16 * tt + ln16;
            #pragma unroll
            for (int r = 0; r < 4; r++)
                gbuf[n * 17 + 4 * q + r] = acc[r];
        }
        __syncthreads();                     // gbuf ready
        if (tid < 160) {
            float hh[2][4];
            #pragma unroll
            for (int e = 0; e < 2; e++) {
                int u = 2 * ej + e;
                #pragma unroll
                for (int mm = 0; mm < 4; mm++) {
                    int m = 4 * emg + mm;
                    float zi = gbuf[(u      ) * 17 + m] + bia[e][0];
                    float zf = gbuf[( 80 + u) * 17 + m] + bia[e][1];
                    float zg = gbuf[(160 + u) * 17 + m] + bia[e][2];
                    float zo = gbuf[(240 + u) * 17 + m] + bia[e][3];
                    float c = fmaf(sigm(zf), cst[e][mm], sigm(zi) * tanh_(zg));
                    cst[e][mm] = c;
                    hh[e][mm] = sigm(zo) * tanh_(c);
                }
            }
            #pragma unroll
            for (int mm = 0; mm < 4; mm++) {
                int m = 4 * emg + mm;
                st[m * 64 + (((ej >> 2) ^ (m & 7)) << 2) + (ej & 3)] =
                    packh(hh[0][mm], hh[1][mm]);
                h1dw[((size_t)t * BATCH + b0 + m) * 40 + ej] =
                    packh(fmaxf(hh[0][mm], 0.f), fmaxf(hh[1][mm], 0.f));
            }
        }
        if (tid < 16 && t + 1 < T_STEPS)
            st[tid * 64 + ((10 ^ (tid & 7)) << 2)] = packh(xs[tid][t + 1], 0.f);
    }
}

// ---------------------------------------------------------------------------
// LSTM layer 2, MFMA. 64 blocks x 320 threads, M=16. Wave wv owns rows
// [80wv,80wv+80) = 5 N-tiles; B-frags 5x6x4 = 120 VGPR ((320,1): cap 512).
// K=192: relu_h1(80) staged from global w/ prefetch, h2(100), pad(12).
// ---------------------------------------------------------------------------
__global__ __launch_bounds__(320, 1)
void lstm2_kernel(const unsigned int* __restrict__ h1dw,
                  const _Float16* __restrict__ wpad2,
                  const float* __restrict__ b_ih2,
                  const float* __restrict__ b_hh2,
                  float* __restrict__ h2last)
{
    const int tid  = threadIdx.x;
    const int lane = tid & 63;
    const int wv   = tid >> 6;
    const int ln16 = lane & 15;
    const int q    = lane >> 4;
    const int b0   = blockIdx.x * 16;

    f16x8 bw[5][6];
    {
        const uint4* wp = (const uint4*)wpad2;   // row = 24 uint4 groups
        #pragma unroll
        for (int tt = 0; tt < 5; tt++) {
            int r = 80 * wv + 16 * tt + ln16;
            #pragma unroll
            for (int kk = 0; kk < 6; kk++)
                bw[tt][kk] = __builtin_bit_cast(f16x8, wp[r * 24 + 4 * kk + q]);
        }
    }

    __shared__ unsigned int st[16 * 96];     // 6KB
    __shared__ float gbuf[400 * 17];         // 27.2KB

    for (int i = tid; i < 16 * 96; i += 320) st[i] = 0u;

    const int ej = tid % 50, emg = (tid / 50) & 3;   // tid<200 epilogue
    float cst[2][4] = {};
    float bia[2][4];
    if (tid < 200) {
        #pragma unroll
        for (int e = 0; e < 2; e++) {
            int u = 2 * ej + e;
            #pragma unroll
            for (int g = 0; g < 4; g++)
                bia[e][g] = b_ih2[g * 100 + u] + b_hh2[g * 100 + u];
        }
    }

    // h1 stagers: all 320 threads, items (m0,d0) and (m1,d0)
    const int m0 = tid / 40, d0 = tid % 40, m1 = m0 + 8;
    const int sw0 = m0 * 96 + (((d0 >> 2) ^ (m0 & 7)) << 2) + (d0 & 3);
    const int sw1 = m1 * 96 + (((d0 >> 2) ^ (m1 & 7)) << 2) + (d0 & 3);
    st[sw0] = h1dw[((size_t)b0 + m0) * 40 + d0];          // h1(0)
    st[sw1] = h1dw[((size_t)b0 + m1) * 40 + d0];
    unsigned int pf0 = h1dw[((size_t)BATCH + b0 + m0) * 40 + d0];   // h1(1)
    unsigned int pf1 = h1dw[((size_t)BATCH + b0 + m1) * 40 + d0];

    for (int t = 0; t < T_STEPS; t++) {
        __syncthreads();                     // state(t) ready
        f16x8 af[6];
        #pragma unroll
        for (int kk = 0; kk < 6; kk++) {
            int g = 4 * kk + q;
            af[kk] = __builtin_bit_cast(f16x8,
                *(const uint4*)&st[ln16 * 96 + ((g ^ (ln16 & 7)) << 2)]);
        }
        #pragma unroll
        for (int tt = 0; tt < 5; tt++) {
            f32x4 acc = {0.f, 0.f, 0.f, 0.f};
            #pragma unroll
            for (int kk = 0; kk < 6; kk++)
                acc = __builtin_amdgcn_mfma_f32_16x16x32_f16(af[kk], bw[tt][kk], acc, 0, 0, 0);
            int n = 80 * wv + 16 * tt + ln16;
            #pragma unroll
            for (int r = 0; r < 4; r++)
                gbuf[n * 17 + 4 * q + r] = acc[r];
        }
        __syncthreads();                     // gbuf ready
        if (tid < 200) {
            float hh[2][4];
            #pragma unroll
            for (int e = 0; e < 2; e++) {
                int u = 2 * ej + e;
                #pragma unroll
                for (int mm = 0; mm < 4; mm++) {
                    int m = 4 * emg + mm;
                    float zi = gbuf[(u      ) * 17 + m] + bia[e][0];
                    float zf = gbuf[(100 + u) * 17 + m] + bia[e][1];
                    float zg = gbuf[(200 + u) * 17 + m] + bia[e][2];
                    float zo = gbuf[(300 + u) * 17 + m] + bia[e][3];
                    float c = fmaf(sigm(zf), cst[e][mm], sigm(zi) * tanh_(zg));
                    cst[e][mm] = c;
                    hh[e][mm] = sigm(zo) * tanh_(c);
                }
            }
            const int d = 40 + ej;           // h2 pair dword
            #pragma unroll
            for (int mm = 0; mm < 4; mm++) {
                int m = 4 * emg + mm;
                st[m * 96 + (((d >> 2) ^ (m & 7)) << 2) + (d & 3)] =
                    packh(hh[0][mm], hh[1][mm]);
                if (t == T_STEPS - 1) {
                    h2last[(size_t)(b0 + m) * HD2 + 2 * ej]     = fmaxf(hh[0][mm], 0.f);
                    h2last[(size_t)(b0 + m) * HD2 + 2 * ej + 1] = fmaxf(hh[1][mm], 0.f);
                }
            }
        }
        if (t + 1 < T_STEPS) {
            st[sw0] = pf0;
            st[sw1] = pf1;
            if (t + 2 < T_STEPS) {
                pf0 = h1dw[((size_t)(t + 2) * BATCH + b0 + m0) * 40 + d0];
                pf1 = h1dw[((size_t)(t + 2) * BATCH + b0 + m1) * 40 + d0];
            }
        }
    }
}

// ---------------------------------------------------------------------------
// Head: out[b] = W_l2 @ relu(W_l1 @ h2last[b] + b_l1) + b_l2
// ---------------------------------------------------------------------------
__global__ __launch_bounds__(64)
void head_kernel(const float* __restrict__ h2last,
                 const float* __restrict__ W_l1,
                 const float* __restrict__ b_l1,
                 const float* __restrict__ W_l2,
                 const float* __restrict__ b_l2,
                 float* __restrict__ out)
{
    int b = blockIdx.x * 64 + threadIdx.x;
    if (b >= BATCH) return;
    const float* h = h2last + (size_t)b * HD2;
    float o = b_l2[0];
#pragma unroll
    for (int u = 0; u < 10; u++) {
        float s = b_l1[u];
#pragma unroll
        for (int k = 0; k < HD2; k++) s = fmaf(W_l1[u * HD2 + k], h[k], s);
        o = fmaf(W_l2[u], fmaxf(s, 0.f), o);
    }
    out[b] = o;
}

extern "C" void kernel_launch(void* const* d_in, const int* in_sizes, int n_in,
                              void* d_out, int out_size, void* d_ws, size_t ws_size,
                              hipStream_t stream)
{
    const float* x     = (const float*)d_in[0];
    const float* W_ih1 = (const float*)d_in[1];
    const float* W_hh1 = (const float*)d_in[2];
    const float* b_ih1 = (const float*)d_in[3];
    const float* b_hh1 = (const float*)d_in[4];
    const float* W_ih2 = (const float*)d_in[5];
    const float* W_hh2 = (const float*)d_in[6];
    const float* b_ih2 = (const float*)d_in[7];
    const float* b_hh2 = (const float*)d_in[8];
    const float* W_l1  = (const float*)d_in[9];
    const float* b_l1  = (const float*)d_in[10];
    const float* W_l2  = (const float*)d_in[11];
    const float* b_l2  = (const float*)d_in[12];
    float* out = (float*)d_out;

    // ws: h1relu dwords [t][b][40] (84MB) | h2last f32 | wpad1 | wpad2
    char* p = (char*)d_ws;
    auto take = [&](size_t n) { char* q = p; p += (n + 255) & ~(size_t)255; return q; };
    unsigned int* h1dw  = (unsigned int*)take((size_t)T_STEPS * BATCH * 40 * 4);
    float*        h2last= (float*)take((size_t)BATCH * HD2 * 4);
    _Float16*     wpad1 = (_Float16*)take((size_t)320 * W1ROW * 2);
    _Float16*     wpad2 = (_Float16*)take((size_t)400 * W2ROW * 2);

    int prep_n = 320 * W1ROW + 400 * W2ROW;
    hipLaunchKernelGGL(prep_kernel, dim3((prep_n + 255) / 256), dim3(256), 0, stream,
                       W_ih1, W_hh1, W_ih2, W_hh2, wpad1, wpad2);
    hipLaunchKernelGGL(lstm1_kernel, dim3(BATCH / 16), dim3(320), 0, stream,
                       x, wpad1, b_ih1, b_hh1, h1dw);
    hipLaunchKernelGGL(lstm2_kernel, dim3(BATCH / 16), dim3(320), 0, stream,
                       h1dw, wpad2, b_ih2, b_hh2, h2last);
    hipLaunchKernelGGL(head_kernel, dim3(BATCH / 64), dim3(64), 0, stream,
                       h2last, W_l1, b_l1, W_l2, b_l2, out);
}